// Round 7
// baseline (4765.781 us; speedup 1.0000x reference)
//
#include <hip/hip_runtime.h>

#define HID 128
#define PROW 104   // P row: src-half at [0..49], dst-half at [52..101]
#define KC 32      // K-chunk of the edge GEMM
#define NKC 4      // 128/KC

// direct global->LDS DMA, 16B per lane (dest = wave-uniform base + lane*16)
__device__ __forceinline__ void gload16(const void* g, void* l) {
  __builtin_amdgcn_global_load_lds((const __attribute__((address_space(1))) void*)g,
                                   (__attribute__((address_space(3))) void*)l, 16, 0, 0);
}

// ---------- detect int32 vs int64 edge_index layout ----------
__global__ void detect_idx_kernel(const unsigned int* __restrict__ p, int* __restrict__ flag) {
  __shared__ int s;
  if (threadIdx.x == 0) s = 0;
  __syncthreads();
  if (p[2 * threadIdx.x + 1] != 0u) atomicOr(&s, 1);
  __syncthreads();
  if (threadIdx.x == 0) *flag = s;   // 1 -> int32 layout, 0 -> int64 layout
}

// ---------- node precompute: P[n][half*52+j] = relu(x[n]) @ W1[half*128 .. +127][j] ----------
__global__ __launch_bounds__(256, 4)
void node_pre_kernel(const float* __restrict__ x, const float* __restrict__ W1,
                     float* __restrict__ P, int n_nodes) {
  __shared__ __align__(16) float a_s[32][132];
  __shared__ __align__(16) float w_s[32][64];
  const int t = threadIdx.x;
  const int half = blockIdx.y;
  const int n0 = blockIdx.x * 128;
  const int jt = t & 15, rt = t >> 4;
  float acc[8][4];
#pragma unroll
  for (int i = 0; i < 8; ++i)
#pragma unroll
    for (int q = 0; q < 4; ++q) acc[i][q] = 0.f;

  for (int kc = 0; kc < 4; ++kc) {
#pragma unroll
    for (int i = 0; i < 4; ++i) {
      int f = t + 256 * i;
      int e = f >> 3;
      int k4 = (f & 7) << 2;
      int n = n0 + e;
      float4 v = make_float4(0.f, 0.f, 0.f, 0.f);
      if (n < n_nodes) v = *(const float4*)&x[(long)n * HID + kc * 32 + k4];
      a_s[k4 + 0][e] = fmaxf(v.x, 0.f);
      a_s[k4 + 1][e] = fmaxf(v.y, 0.f);
      a_s[k4 + 2][e] = fmaxf(v.z, 0.f);
      a_s[k4 + 3][e] = fmaxf(v.w, 0.f);
    }
#pragma unroll
    for (int i = 0; i < 8; ++i) {
      int f = t + 256 * i;
      int k = f >> 6, j = f & 63;
      float w = 0.f;
      if (j < 50) w = W1[(half * 128 + kc * 32 + k) * 50 + j];
      w_s[k][j] = w;
    }
    __syncthreads();
#pragma unroll 8
    for (int kk = 0; kk < 32; ++kk) {
      float4 w4 = *(const float4*)&w_s[kk][jt * 4];
      float4 a0 = *(const float4*)&a_s[kk][rt * 8];
      float4 a1 = *(const float4*)&a_s[kk][rt * 8 + 4];
      float av[8] = {a0.x, a0.y, a0.z, a0.w, a1.x, a1.y, a1.z, a1.w};
      float wv[4] = {w4.x, w4.y, w4.z, w4.w};
#pragma unroll
      for (int ri = 0; ri < 8; ++ri)
#pragma unroll
        for (int q = 0; q < 4; ++q) acc[ri][q] = fmaf(av[ri], wv[q], acc[ri][q]);
    }
    __syncthreads();
  }
  int jb = jt * 4;
  if (jb < 50) {
#pragma unroll
    for (int ri = 0; ri < 8; ++ri) {
      int n = n0 + rt * 8 + ri;
      if (n < n_nodes) {
#pragma unroll
        for (int q = 0; q < 4; ++q) {
          int j = jb + q;
          if (j < 50) P[(long)n * PROW + half * 52 + j] = acc[ri][q];
        }
      }
    }
  }
}

// ---------- fused edge kernel: thread-per-edge-half, DMA-staged ea, scalar weights ----------
__global__ __launch_bounds__(256, 4)
void edge_kernel(const float* __restrict__ ea, const void* __restrict__ eidx,
                 const float* __restrict__ W1, const float* __restrict__ b1,
                 const float* __restrict__ W2, const float* __restrict__ b2,
                 const float* __restrict__ W3, const float* __restrict__ b3,
                 const float* __restrict__ P, const int* __restrict__ flag,
                 float* __restrict__ out, int n_edges) {
  __shared__ __align__(16) union SU {
    float a[2][128][KC];   // 32 KB, [buf][edge][k-slot], XOR-swizzled 16B slots
    float h1[128][52];     // 26.6 KB, live after GEMM
  } u;
  __shared__ float p_s[2][128];

  const int t = threadIdx.x;
  const int e0 = blockIdx.x * 128;
  const int e = t & 127;          // edge within tile
  const int h = t >> 7;           // column half (wave-uniform: waves 0,1 -> 0; waves 2,3 -> 1)
  const int wv = t >> 6;
  const int ln = t & 63;
  const bool full = (e0 + 128 <= n_edges);

  // stage one K-chunk of ea into u.a[buf]; physical 16B slot s of row r holds global slot s^(r&7)
  auto stage = [&](int buf, int kc) {
    if (full) {
#pragma unroll
      for (int c = 0; c < 4; ++c) {
        int f = c * 256 + wv * 64 + ln;
        int row = f >> 3, sl = ln & 7;
        int gs = sl ^ (row & 7);
        gload16(&ea[(long)(e0 + row) * HID + kc * KC + gs * 4],
                &u.a[buf][row][sl * 4]);
      }
    } else {
      for (int f = t; f < 1024; f += 256) {   // 128 rows x 8 slots
        int row = f >> 3, s = f & 7;
        float4 v = make_float4(0.f, 0.f, 0.f, 0.f);
        if (e0 + row < n_edges) v = *(const float4*)&ea[(long)(e0 + row) * HID + kc * KC + s * 4];
        *(float4*)&u.a[buf][row][(s ^ (row & 7)) << 2] = v;
      }
    }
  };

  // ---- prologue: edge indices (per-thread regs), first two DMA chunks ----
  const int use32 = *flag;
  int sidx = 0, didx = 0;
  if (e0 + e < n_edges) {
    if (use32) {
      sidx = ((const int*)eidx)[e0 + e];
      didx = ((const int*)eidx)[(long)n_edges + e0 + e];
    } else {
      sidx = (int)((const long long*)eidx)[e0 + e];
      didx = (int)((const long long*)eidx)[(long)n_edges + e0 + e];
    }
  }
  stage(0, 0);
  stage(1, 1);
  __syncthreads();   // drains both DMA chunks

  // ---- GEMM: h1[25] accumulators in regs; W1 via wave-uniform scalar loads ----
  float h1r[25];
#pragma unroll
  for (int jj = 0; jj < 25; ++jj) h1r[jj] = 0.f;

  const float* __restrict__ w1c = W1 + (long)256 * 50 + h * 25;   // W1c rows, this half's cols

#pragma unroll 1
  for (int kc = 0; kc < NKC; ++kc) {
    const int cur = kc & 1;
#pragma unroll
    for (int q = 0; q < 8; ++q) {
      float4 a4 = *(const float4*)&u.a[cur][e][(q ^ (e & 7)) << 2];
      float am[4] = {a4.x, a4.y, a4.z, a4.w};
#pragma unroll
      for (int kk = 0; kk < 4; ++kk) {
        const float* wrow = &w1c[(kc * KC + q * 4 + kk) * 50];   // uniform -> s_load
#pragma unroll
        for (int jj = 0; jj < 25; ++jj) h1r[jj] = fmaf(am[kk], wrow[jj], h1r[jj]);
      }
    }
    __syncthreads();                       // all reads of buf[cur] done; chunk kc+1 arrived
    if (kc + 2 < NKC) stage(cur, kc + 2);  // lands during next chunk's compute
  }

  // ---- layer-1 finish: P gather (per-lane, L2/L3-resident) + bias + relu -> h1_s ----
  {
    const float* ps = &P[(long)sidx * PROW + h * 25];
    const float* pd = &P[(long)didx * PROW + 52 + h * 25];
#pragma unroll
    for (int jj = 0; jj < 25; ++jj) {
      float v = h1r[jj] + ps[jj] + pd[jj] + b1[h * 25 + jj];   // b1 uniform -> scalar
      u.h1[e][h * 25 + jj] = fmaxf(v, 0.f);                    // union safe: after final barrier
    }
  }
  __syncthreads();

  // ---- layers 2 + 3: two threads per edge, 13/12 output cols; W2/W3/b2 wave-uniform ----
  const int jb2 = h * 13;
  float acc2[13];
#pragma unroll
  for (int jj = 0; jj < 13; ++jj) {
    int j2 = jb2 + jj;
    acc2[jj] = (j2 < 25) ? b2[j2] : 0.f;
  }
  for (int k2 = 0; k2 < 50; ++k2) {
    float v = u.h1[e][k2];
#pragma unroll
    for (int jj = 0; jj < 13; ++jj) {
      int j2 = jb2 + jj;
      if (j2 < 25) acc2[jj] = fmaf(v, W2[k2 * 25 + j2], acc2[jj]);
    }
  }
  float part = 0.f;
#pragma unroll
  for (int jj = 0; jj < 13; ++jj) {
    int j2 = jb2 + jj;
    if (j2 < 25) part += fmaxf(acc2[jj], 0.f) * W3[j2];
  }
  p_s[h][e] = part;
  __syncthreads();
  if (t < 128 && (e0 + t) < n_edges) out[e0 + t] = p_s[0][t] + p_s[1][t] + b3[0];
}

// ---------- naive fallback (only if ws too small for P) ----------
__global__ __launch_bounds__(256, 2)
void edge_naive_kernel(const float* __restrict__ x, const float* __restrict__ ea,
                       const void* __restrict__ eidx,
                       const float* __restrict__ W1, const float* __restrict__ b1,
                       const float* __restrict__ W2, const float* __restrict__ b2,
                       const float* __restrict__ W3, const float* __restrict__ b3,
                       const int* __restrict__ flag, int use32_const,
                       float* __restrict__ out, int n_edges) {
  int e = blockIdx.x * blockDim.x + threadIdx.x;
  if (e >= n_edges) return;
  int use32 = flag ? *flag : use32_const;
  long s, d;
  if (use32) {
    s = ((const int*)eidx)[e];
    d = ((const int*)eidx)[(long)n_edges + e];
  } else {
    s = (long)((const long long*)eidx)[e];
    d = (long)((const long long*)eidx)[(long)n_edges + e];
  }
  float h1[50];
#pragma unroll
  for (int j = 0; j < 50; ++j) h1[j] = b1[j];
  for (int k = 0; k < 128; ++k) {
    float v = fmaxf(x[s * HID + k], 0.f);
#pragma unroll
    for (int j = 0; j < 50; ++j) h1[j] = fmaf(v, W1[k * 50 + j], h1[j]);
  }
  for (int k = 0; k < 128; ++k) {
    float v = fmaxf(x[d * HID + k], 0.f);
#pragma unroll
    for (int j = 0; j < 50; ++j) h1[j] = fmaf(v, W1[(128 + k) * 50 + j], h1[j]);
  }
  for (int k = 0; k < 128; ++k) {
    float v = ea[(long)e * HID + k];
#pragma unroll
    for (int j = 0; j < 50; ++j) h1[j] = fmaf(v, W1[(256 + k) * 50 + j], h1[j]);
  }
  float o = b3[0];
  for (int j2 = 0; j2 < 25; ++j2) {
    float h2 = b2[j2];
#pragma unroll 10
    for (int k = 0; k < 50; ++k) h2 = fmaf(fmaxf(h1[k], 0.f), W2[k * 25 + j2], h2);
    o = fmaf(fmaxf(h2, 0.f), W3[j2], o);
  }
  out[e] = o;
}

extern "C" void kernel_launch(void* const* d_in, const int* in_sizes, int n_in,
                              void* d_out, int out_size, void* d_ws, size_t ws_size,
                              hipStream_t stream) {
  const float* x  = (const float*)d_in[0];
  const float* ea = (const float*)d_in[1];
  const void*  ei = d_in[2];
  const float* W1 = (const float*)d_in[3];
  const float* b1 = (const float*)d_in[4];
  const float* W2 = (const float*)d_in[5];
  const float* b2 = (const float*)d_in[6];
  const float* W3 = (const float*)d_in[7];
  const float* b3 = (const float*)d_in[8];
  float* out = (float*)d_out;
  const int n_nodes = in_sizes[0] / HID;
  const int n_edges = in_sizes[1] / HID;
  const size_t pbytes = (size_t)n_nodes * PROW * sizeof(float);

  if (ws_size >= pbytes + sizeof(int)) {
    float* P  = (float*)d_ws;
    int* flag = (int*)((char*)d_ws + pbytes);
    hipLaunchKernelGGL(detect_idx_kernel, dim3(1), dim3(256), 0, stream,
                       (const unsigned int*)ei, flag);
    dim3 gp((n_nodes + 127) / 128, 2);
    hipLaunchKernelGGL(node_pre_kernel, gp, dim3(256), 0, stream, x, W1, P, n_nodes);
    dim3 ge((n_edges + 127) / 128);
    hipLaunchKernelGGL(edge_kernel, ge, dim3(256), 0, stream,
                       ea, ei, W1, b1, W2, b2, W3, b3, P, flag, out, n_edges);
  } else if (ws_size >= sizeof(int)) {
    int* flag = (int*)d_ws;
    hipLaunchKernelGGL(detect_idx_kernel, dim3(1), dim3(256), 0, stream,
                       (const unsigned int*)ei, flag);
    hipLaunchKernelGGL(edge_naive_kernel, dim3((n_edges + 255) / 256), dim3(256), 0, stream,
                       x, ea, ei, W1, b1, W2, b2, W3, b3, flag, 1, out, n_edges);
  } else {
    hipLaunchKernelGGL(edge_naive_kernel, dim3((n_edges + 255) / 256), dim3(256), 0, stream,
                       x, ea, ei, W1, b1, W2, b2, W3, b3, (const int*)nullptr, 1, out, n_edges);
  }
}

// Round 8
// 419.051 us; speedup vs baseline: 11.3728x; 11.3728x over previous
//
#include <hip/hip_runtime.h>

#define HID 128
#define PROW 104   // P row: src-half at [0..49], dst-half at [52..101]
#define KC 16      // K-chunk of the edge GEMM
#define NKC 8      // 128/KC

// ---------- detect int32 vs int64 edge_index layout ----------
__global__ void detect_idx_kernel(const unsigned int* __restrict__ p, int* __restrict__ flag) {
  __shared__ int s;
  if (threadIdx.x == 0) s = 0;
  __syncthreads();
  if (p[2 * threadIdx.x + 1] != 0u) atomicOr(&s, 1);
  __syncthreads();
  if (threadIdx.x == 0) *flag = s;   // 1 -> int32 layout, 0 -> int64 layout
}

// ---------- node precompute: P[n][half*52+j] = relu(x[n]) @ W1[half*128 .. +127][j] ----------
__global__ __launch_bounds__(256, 4)
void node_pre_kernel(const float* __restrict__ x, const float* __restrict__ W1,
                     float* __restrict__ P, int n_nodes) {
  __shared__ __align__(16) float a_s[32][132];
  __shared__ __align__(16) float w_s[32][64];
  const int t = threadIdx.x;
  const int half = blockIdx.y;
  const int n0 = blockIdx.x * 128;
  const int jt = t & 15, rt = t >> 4;
  float acc[8][4];
#pragma unroll
  for (int i = 0; i < 8; ++i)
#pragma unroll
    for (int q = 0; q < 4; ++q) acc[i][q] = 0.f;

  for (int kc = 0; kc < 4; ++kc) {
#pragma unroll
    for (int i = 0; i < 4; ++i) {
      int f = t + 256 * i;
      int e = f >> 3;
      int k4 = (f & 7) << 2;
      int n = n0 + e;
      float4 v = make_float4(0.f, 0.f, 0.f, 0.f);
      if (n < n_nodes) v = *(const float4*)&x[(long)n * HID + kc * 32 + k4];
      a_s[k4 + 0][e] = fmaxf(v.x, 0.f);
      a_s[k4 + 1][e] = fmaxf(v.y, 0.f);
      a_s[k4 + 2][e] = fmaxf(v.z, 0.f);
      a_s[k4 + 3][e] = fmaxf(v.w, 0.f);
    }
#pragma unroll
    for (int i = 0; i < 8; ++i) {
      int f = t + 256 * i;
      int k = f >> 6, j = f & 63;
      float w = 0.f;
      if (j < 50) w = W1[(half * 128 + kc * 32 + k) * 50 + j];
      w_s[k][j] = w;
    }
    __syncthreads();
#pragma unroll 8
    for (int kk = 0; kk < 32; ++kk) {
      float4 w4 = *(const float4*)&w_s[kk][jt * 4];
      float4 a0 = *(const float4*)&a_s[kk][rt * 8];
      float4 a1 = *(const float4*)&a_s[kk][rt * 8 + 4];
      float av[8] = {a0.x, a0.y, a0.z, a0.w, a1.x, a1.y, a1.z, a1.w};
      float wv[4] = {w4.x, w4.y, w4.z, w4.w};
#pragma unroll
      for (int ri = 0; ri < 8; ++ri)
#pragma unroll
        for (int q = 0; q < 4; ++q) acc[ri][q] = fmaf(av[ri], wv[q], acc[ri][q]);
    }
    __syncthreads();
  }
  int jb = jt * 4;
  if (jb < 50) {
#pragma unroll
    for (int ri = 0; ri < 8; ++ri) {
      int n = n0 + rt * 8 + ri;
      if (n < n_nodes) {
#pragma unroll
        for (int q = 0; q < 4; ++q) {
          int j = jb + q;
          if (j < 50) P[(long)n * PROW + half * 52 + j] = acc[ri][q];
        }
      }
    }
  }
}

// ---------- fused edge kernel: R2 shell + once-staged W1c + 2-float4 ea prefetch ----------
__global__ __launch_bounds__(256, 4)
void edge_kernel(const float* __restrict__ ea, const void* __restrict__ eidx,
                 const float* __restrict__ W1, const float* __restrict__ b1,
                 const float* __restrict__ W2, const float* __restrict__ b2,
                 const float* __restrict__ W3, const float* __restrict__ b3,
                 const float* __restrict__ P, const int* __restrict__ flag,
                 float* __restrict__ out, int n_edges) {
  // GEMM-live tiles union h1 (live only after GEMM)
  __shared__ __align__(16) union SU {
    struct {
      float w[128][52];    // 26.6 KB: all of W1c, staged once in prologue
      float a[KC][132];    // 8.4 KB: current ea K-chunk, transposed [k][edge]
    } gs;
    float h1[128][53];     // 27.1 KB
  } u;
  __shared__ float b1_s[64];
  __shared__ float p_s[2][128];
  __shared__ int src_s[128], dst_s[128];

  const int t = threadIdx.x;
  const int e0 = blockIdx.x * 128;
  const int jt = t & 15, rt = t >> 4;
  const int wj = (jt <= 12) ? jt * 4 : 48;   // clamped W col; lanes 13-15 duplicate, writes guarded

  // ---- prologue ----
  if (t < 64) b1_s[t] = (t < 50) ? b1[t] : 0.f;
  const int use32 = *flag;
  if (t < 128) {
    int e = e0 + t;
    int v = 0;
    if (e < n_edges) v = use32 ? ((const int*)eidx)[e] : (int)((const long long*)eidx)[e];
    src_s[t] = v;
  } else {
    int e = e0 + (t - 128);
    int v = 0;
    if (e < n_edges)
      v = use32 ? ((const int*)eidx)[(long)n_edges + e] : (int)((const long long*)eidx)[(long)n_edges + e];
    dst_s[t - 128] = v;
  }
  // stage all of W1c once (rows 256..383 of W1), cols padded 50->52 (coalesced scalar loads)
  for (int f = t; f < 128 * 52; f += 256) {
    int r = f / 52, j = f % 52;
    u.gs.w[r][j] = (j < 50) ? W1[(256 + r) * 50 + j] : 0.f;
  }
  // issue ea chunk 0 into prefetch regs (2 float4/thread; latency overlaps w-staging above)
  const int ae = t >> 1;              // 0..127 edge (2 threads/edge)
  const int ak = (t & 1) << 3;        // k-offset 0 or 8
  float4 av0, av1;
  {
    float4 z = make_float4(0.f, 0.f, 0.f, 0.f);
    av0 = z; av1 = z;
    if (e0 + ae < n_edges) {
      av0 = *(const float4*)&ea[(long)(e0 + ae) * HID + ak];
      av1 = *(const float4*)&ea[(long)(e0 + ae) * HID + ak + 4];
    }
  }

  // ---- GEMM: ds_write av | sync | issue av(kc+1) | compute | sync ----
  float acc[8][4];
#pragma unroll
  for (int i = 0; i < 8; ++i)
#pragma unroll
    for (int q = 0; q < 4; ++q) acc[i][q] = 0.f;

#pragma unroll 1
  for (int kc = 0; kc < NKC; ++kc) {
    // scatter prefetched chunk into transposed a-tile
    u.gs.a[ak + 0][ae] = av0.x;
    u.gs.a[ak + 1][ae] = av0.y;
    u.gs.a[ak + 2][ae] = av0.z;
    u.gs.a[ak + 3][ae] = av0.w;
    u.gs.a[ak + 4][ae] = av1.x;
    u.gs.a[ak + 5][ae] = av1.y;
    u.gs.a[ak + 6][ae] = av1.z;
    u.gs.a[ak + 7][ae] = av1.w;
    __syncthreads();                 // a-tile(kc) visible
    if (kc + 1 < NKC) {              // issue next chunk; arrives during compute below
      float4 z = make_float4(0.f, 0.f, 0.f, 0.f);
      float4 n0 = z, n1 = z;
      if (e0 + ae < n_edges) {
        n0 = *(const float4*)&ea[(long)(e0 + ae) * HID + (kc + 1) * KC + ak];
        n1 = *(const float4*)&ea[(long)(e0 + ae) * HID + (kc + 1) * KC + ak + 4];
      }
      av0 = n0; av1 = n1;
    }
#pragma unroll
    for (int kk = 0; kk < KC; ++kk) {
      float4 w4 = *(const float4*)&u.gs.w[kc * KC + kk][wj];
      float4 a0 = *(const float4*)&u.gs.a[kk][rt * 8];
      float4 a1 = *(const float4*)&u.gs.a[kk][rt * 8 + 4];
      float am[8] = {a0.x, a0.y, a0.z, a0.w, a1.x, a1.y, a1.z, a1.w};
      float wv[4] = {w4.x, w4.y, w4.z, w4.w};
#pragma unroll
      for (int ri = 0; ri < 8; ++ri)
#pragma unroll
        for (int q = 0; q < 4; ++q) acc[ri][q] = fmaf(am[ri], wv[q], acc[ri][q]);
    }
    __syncthreads();                 // reads of a-tile(kc) done before next ds_write
  }

  // ---- layer-1 epilogue: P gather + bias + relu -> h1 (union safe after final barrier) ----
  const int jb = jt * 4;
  if (jb < 50) {
#pragma unroll
    for (int ri = 0; ri < 8; ++ri) {
      int e = rt * 8 + ri;
      long s = src_s[e], d = dst_s[e];
      float4 pa = *(const float4*)&P[s * PROW + jb];
      float4 pb = *(const float4*)&P[d * PROW + 52 + jb];
      float par[4] = {pa.x, pa.y, pa.z, pa.w};
      float pbr[4] = {pb.x, pb.y, pb.z, pb.w};
#pragma unroll
      for (int q = 0; q < 4; ++q) {
        int j = jb + q;
        if (j < 50) {
          float v = acc[ri][q] + par[q] + pbr[q] + b1_s[j];
          u.h1[e][j] = fmaxf(v, 0.f);
        }
      }
    }
  }
  __syncthreads();

  // ---- layers 2 + 3: two threads per edge; W2/W3/b2 wave-uniform -> scalar loads ----
  const int e2 = t & 127, hh = t >> 7;
  const int jb2 = hh * 13;
  float acc2[13];
#pragma unroll
  for (int jj = 0; jj < 13; ++jj) {
    int j2 = jb2 + jj;
    acc2[jj] = (j2 < 25) ? b2[j2] : 0.f;
  }
  for (int k2 = 0; k2 < 50; ++k2) {
    float v = u.h1[e2][k2];
#pragma unroll
    for (int jj = 0; jj < 13; ++jj) {
      int j2 = jb2 + jj;
      if (j2 < 25) acc2[jj] = fmaf(v, W2[k2 * 25 + j2], acc2[jj]);
    }
  }
  float part = 0.f;
#pragma unroll
  for (int jj = 0; jj < 13; ++jj) {
    int j2 = jb2 + jj;
    if (j2 < 25) part += fmaxf(acc2[jj], 0.f) * W3[j2];
  }
  p_s[hh][e2] = part;
  __syncthreads();
  if (t < 128 && (e0 + t) < n_edges) out[e0 + t] = p_s[0][t] + p_s[1][t] + b3[0];
}

// ---------- naive fallback (only if ws too small for P) ----------
__global__ __launch_bounds__(256, 2)
void edge_naive_kernel(const float* __restrict__ x, const float* __restrict__ ea,
                       const void* __restrict__ eidx,
                       const float* __restrict__ W1, const float* __restrict__ b1,
                       const float* __restrict__ W2, const float* __restrict__ b2,
                       const float* __restrict__ W3, const float* __restrict__ b3,
                       const int* __restrict__ flag, int use32_const,
                       float* __restrict__ out, int n_edges) {
  int e = blockIdx.x * blockDim.x + threadIdx.x;
  if (e >= n_edges) return;
  int use32 = flag ? *flag : use32_const;
  long s, d;
  if (use32) {
    s = ((const int*)eidx)[e];
    d = ((const int*)eidx)[(long)n_edges + e];
  } else {
    s = (long)((const long long*)eidx)[e];
    d = (long)((const long long*)eidx)[(long)n_edges + e];
  }
  float h1[50];
#pragma unroll
  for (int j = 0; j < 50; ++j) h1[j] = b1[j];
  for (int k = 0; k < 128; ++k) {
    float v = fmaxf(x[s * HID + k], 0.f);
#pragma unroll
    for (int j = 0; j < 50; ++j) h1[j] = fmaf(v, W1[k * 50 + j], h1[j]);
  }
  for (int k = 0; k < 128; ++k) {
    float v = fmaxf(x[d * HID + k], 0.f);
#pragma unroll
    for (int j = 0; j < 50; ++j) h1[j] = fmaf(v, W1[(128 + k) * 50 + j], h1[j]);
  }
  for (int k = 0; k < 128; ++k) {
    float v = ea[(long)e * HID + k];
#pragma unroll
    for (int j = 0; j < 50; ++j) h1[j] = fmaf(v, W1[(256 + k) * 50 + j], h1[j]);
  }
  float o = b3[0];
  for (int j2 = 0; j2 < 25; ++j2) {
    float h2 = b2[j2];
#pragma unroll 10
    for (int k = 0; k < 50; ++k) h2 = fmaf(fmaxf(h1[k], 0.f), W2[k * 25 + j2], h2);
    o = fmaf(fmaxf(h2, 0.f), W3[j2], o);
  }
  out[e] = o;
}

extern "C" void kernel_launch(void* const* d_in, const int* in_sizes, int n_in,
                              void* d_out, int out_size, void* d_ws, size_t ws_size,
                              hipStream_t stream) {
  const float* x  = (const float*)d_in[0];
  const float* ea = (const float*)d_in[1];
  const void*  ei = d_in[2];
  const float* W1 = (const float*)d_in[3];
  const float* b1 = (const float*)d_in[4];
  const float* W2 = (const float*)d_in[5];
  const float* b2 = (const float*)d_in[6];
  const float* W3 = (const float*)d_in[7];
  const float* b3 = (const float*)d_in[8];
  float* out = (float*)d_out;
  const int n_nodes = in_sizes[0] / HID;
  const int n_edges = in_sizes[1] / HID;
  const size_t pbytes = (size_t)n_nodes * PROW * sizeof(float);

  if (ws_size >= pbytes + sizeof(int)) {
    float* P  = (float*)d_ws;
    int* flag = (int*)((char*)d_ws + pbytes);
    hipLaunchKernelGGL(detect_idx_kernel, dim3(1), dim3(256), 0, stream,
                       (const unsigned int*)ei, flag);
    dim3 gp((n_nodes + 127) / 128, 2);
    hipLaunchKernelGGL(node_pre_kernel, gp, dim3(256), 0, stream, x, W1, P, n_nodes);
    dim3 ge((n_edges + 127) / 128);
    hipLaunchKernelGGL(edge_kernel, ge, dim3(256), 0, stream,
                       ea, ei, W1, b1, W2, b2, W3, b3, P, flag, out, n_edges);
  } else if (ws_size >= sizeof(int)) {
    int* flag = (int*)d_ws;
    hipLaunchKernelGGL(detect_idx_kernel, dim3(1), dim3(256), 0, stream,
                       (const unsigned int*)ei, flag);
    hipLaunchKernelGGL(edge_naive_kernel, dim3((n_edges + 255) / 256), dim3(256), 0, stream,
                       x, ea, ei, W1, b1, W2, b2, W3, b3, flag, 1, out, n_edges);
  } else {
    hipLaunchKernelGGL(edge_naive_kernel, dim3((n_edges + 255) / 256), dim3(256), 0, stream,
                       x, ea, ei, W1, b1, W2, b2, W3, b3, (const int*)nullptr, 1, out, n_edges);
  }
}

// Round 9
// 407.479 us; speedup vs baseline: 11.6958x; 1.0284x over previous
//
#include <hip/hip_runtime.h>

#define HID 128
#define PROW 104   // P row: src-half at [0..49], dst-half at [52..101]
#define KC 16      // K-chunk of the edge GEMM
#define NKC 8      // 128/KC

// ---------- detect int32 vs int64 edge_index layout ----------
__global__ void detect_idx_kernel(const unsigned int* __restrict__ p, int* __restrict__ flag) {
  __shared__ int s;
  if (threadIdx.x == 0) s = 0;
  __syncthreads();
  if (p[2 * threadIdx.x + 1] != 0u) atomicOr(&s, 1);
  __syncthreads();
  if (threadIdx.x == 0) *flag = s;   // 1 -> int32 layout, 0 -> int64 layout
}

// ---------- node precompute: P[n][half*52+j] = relu(x[n]) @ W1[half*128 .. +127][j] ----------
__global__ __launch_bounds__(256, 4)
void node_pre_kernel(const float* __restrict__ x, const float* __restrict__ W1,
                     float* __restrict__ P, int n_nodes) {
  __shared__ __align__(16) float a_s[32][132];
  __shared__ __align__(16) float w_s[32][64];
  const int t = threadIdx.x;
  const int half = blockIdx.y;
  const int n0 = blockIdx.x * 128;
  const int jt = t & 15, rt = t >> 4;
  float acc[8][4];
#pragma unroll
  for (int i = 0; i < 8; ++i)
#pragma unroll
    for (int q = 0; q < 4; ++q) acc[i][q] = 0.f;

  for (int kc = 0; kc < 4; ++kc) {
#pragma unroll
    for (int i = 0; i < 4; ++i) {
      int f = t + 256 * i;
      int e = f >> 3;
      int k4 = (f & 7) << 2;
      int n = n0 + e;
      float4 v = make_float4(0.f, 0.f, 0.f, 0.f);
      if (n < n_nodes) v = *(const float4*)&x[(long)n * HID + kc * 32 + k4];
      a_s[k4 + 0][e] = fmaxf(v.x, 0.f);
      a_s[k4 + 1][e] = fmaxf(v.y, 0.f);
      a_s[k4 + 2][e] = fmaxf(v.z, 0.f);
      a_s[k4 + 3][e] = fmaxf(v.w, 0.f);
    }
#pragma unroll
    for (int i = 0; i < 8; ++i) {
      int f = t + 256 * i;
      int k = f >> 6, j = f & 63;
      float w = 0.f;
      if (j < 50) w = W1[(half * 128 + kc * 32 + k) * 50 + j];
      w_s[k][j] = w;
    }
    __syncthreads();
#pragma unroll 8
    for (int kk = 0; kk < 32; ++kk) {
      float4 w4 = *(const float4*)&w_s[kk][jt * 4];
      float4 a0 = *(const float4*)&a_s[kk][rt * 8];
      float4 a1 = *(const float4*)&a_s[kk][rt * 8 + 4];
      float av[8] = {a0.x, a0.y, a0.z, a0.w, a1.x, a1.y, a1.z, a1.w};
      float wv[4] = {w4.x, w4.y, w4.z, w4.w};
#pragma unroll
      for (int ri = 0; ri < 8; ++ri)
#pragma unroll
        for (int q = 0; q < 4; ++q) acc[ri][q] = fmaf(av[ri], wv[q], acc[ri][q]);
    }
    __syncthreads();
  }
  int jb = jt * 4;
  if (jb < 50) {
#pragma unroll
    for (int ri = 0; ri < 8; ++ri) {
      int n = n0 + rt * 8 + ri;
      if (n < n_nodes) {
#pragma unroll
        for (int q = 0; q < 4; ++q) {
          int j = jb + q;
          if (j < 50) P[(long)n * PROW + half * 52 + j] = acc[ri][q];
        }
      }
    }
  }
}

// ---------- fused edge kernel: R8 structure, VGPR cap raised to 85 (no spill) ----------
__global__ __launch_bounds__(256, 3)
void edge_kernel(const float* __restrict__ ea, const void* __restrict__ eidx,
                 const float* __restrict__ W1, const float* __restrict__ b1,
                 const float* __restrict__ W2, const float* __restrict__ b2,
                 const float* __restrict__ W3, const float* __restrict__ b3,
                 const float* __restrict__ P, const int* __restrict__ flag,
                 float* __restrict__ out, int n_edges) {
  // GEMM-live tiles union h1 (live only after GEMM)
  __shared__ __align__(16) union SU {
    struct {
      float w[128][52];    // 26.6 KB: all of W1c, staged once in prologue
      float a[KC][132];    // 8.4 KB: current ea K-chunk, transposed [k][edge]
    } gs;
    float h1[128][53];     // 27.1 KB
  } u;
  __shared__ float b1_s[64];
  __shared__ float p_s[2][128];
  __shared__ int src_s[128], dst_s[128];

  const int t = threadIdx.x;
  const int e0 = blockIdx.x * 128;
  const int jt = t & 15, rt = t >> 4;
  const int wj = (jt <= 12) ? jt * 4 : 48;   // clamped W col; lanes 13-15 duplicate, writes guarded

  // ---- prologue ----
  if (t < 64) b1_s[t] = (t < 50) ? b1[t] : 0.f;
  const int use32 = *flag;
  if (t < 128) {
    int e = e0 + t;
    int v = 0;
    if (e < n_edges) v = use32 ? ((const int*)eidx)[e] : (int)((const long long*)eidx)[e];
    src_s[t] = v;
  } else {
    int e = e0 + (t - 128);
    int v = 0;
    if (e < n_edges)
      v = use32 ? ((const int*)eidx)[(long)n_edges + e] : (int)((const long long*)eidx)[(long)n_edges + e];
    dst_s[t - 128] = v;
  }
  // stage all of W1c once (rows 256..383 of W1), cols padded 50->52 (coalesced scalar loads)
  for (int f = t; f < 128 * 52; f += 256) {
    int r = f / 52, j = f % 52;
    u.gs.w[r][j] = (j < 50) ? W1[(256 + r) * 50 + j] : 0.f;
  }
  // issue ea chunk 0 into prefetch regs (2 float4/thread; latency overlaps w-staging above)
  const int ae = t >> 1;              // 0..127 edge (2 threads/edge)
  const int ak = (t & 1) << 3;        // k-offset 0 or 8
  float4 av0, av1;
  {
    float4 z = make_float4(0.f, 0.f, 0.f, 0.f);
    av0 = z; av1 = z;
    if (e0 + ae < n_edges) {
      av0 = *(const float4*)&ea[(long)(e0 + ae) * HID + ak];
      av1 = *(const float4*)&ea[(long)(e0 + ae) * HID + ak + 4];
    }
  }

  // ---- GEMM: ds_write av | sync | issue av(kc+1) | compute | sync ----
  float acc[8][4];
#pragma unroll
  for (int i = 0; i < 8; ++i)
#pragma unroll
    for (int q = 0; q < 4; ++q) acc[i][q] = 0.f;

#pragma unroll 1
  for (int kc = 0; kc < NKC; ++kc) {
    // scatter prefetched chunk into transposed a-tile
    u.gs.a[ak + 0][ae] = av0.x;
    u.gs.a[ak + 1][ae] = av0.y;
    u.gs.a[ak + 2][ae] = av0.z;
    u.gs.a[ak + 3][ae] = av0.w;
    u.gs.a[ak + 4][ae] = av1.x;
    u.gs.a[ak + 5][ae] = av1.y;
    u.gs.a[ak + 6][ae] = av1.z;
    u.gs.a[ak + 7][ae] = av1.w;
    __syncthreads();                 // a-tile(kc) visible
    if (kc + 1 < NKC) {              // issue next chunk; arrives during compute below
      float4 z = make_float4(0.f, 0.f, 0.f, 0.f);
      float4 n0 = z, n1 = z;
      if (e0 + ae < n_edges) {
        n0 = *(const float4*)&ea[(long)(e0 + ae) * HID + (kc + 1) * KC + ak];
        n1 = *(const float4*)&ea[(long)(e0 + ae) * HID + (kc + 1) * KC + ak + 4];
      }
      av0 = n0; av1 = n1;
    }
#pragma unroll
    for (int kk = 0; kk < KC; ++kk) {
      float4 w4 = *(const float4*)&u.gs.w[kc * KC + kk][wj];
      float4 a0 = *(const float4*)&u.gs.a[kk][rt * 8];
      float4 a1 = *(const float4*)&u.gs.a[kk][rt * 8 + 4];
      float am[8] = {a0.x, a0.y, a0.z, a0.w, a1.x, a1.y, a1.z, a1.w};
      float wv[4] = {w4.x, w4.y, w4.z, w4.w};
#pragma unroll
      for (int ri = 0; ri < 8; ++ri)
#pragma unroll
        for (int q = 0; q < 4; ++q) acc[ri][q] = fmaf(am[ri], wv[q], acc[ri][q]);
    }
    __syncthreads();                 // reads of a-tile(kc) done before next ds_write
  }

  // ---- layer-1 epilogue: P gather + bias + relu -> h1 (union safe after final barrier) ----
  const int jb = jt * 4;
  if (jb < 50) {
#pragma unroll
    for (int ri = 0; ri < 8; ++ri) {
      int e = rt * 8 + ri;
      long s = src_s[e], d = dst_s[e];
      float4 pa = *(const float4*)&P[s * PROW + jb];
      float4 pb = *(const float4*)&P[d * PROW + 52 + jb];
      float par[4] = {pa.x, pa.y, pa.z, pa.w};
      float pbr[4] = {pb.x, pb.y, pb.z, pb.w};
#pragma unroll
      for (int q = 0; q < 4; ++q) {
        int j = jb + q;
        if (j < 50) {
          float v = acc[ri][q] + par[q] + pbr[q] + b1_s[j];
          u.h1[e][j] = fmaxf(v, 0.f);
        }
      }
    }
  }
  __syncthreads();

  // ---- layers 2 + 3: two threads per edge; W2/W3/b2 wave-uniform -> scalar loads ----
  const int e2 = t & 127, hh = t >> 7;
  const int jb2 = hh * 13;
  float acc2[13];
#pragma unroll
  for (int jj = 0; jj < 13; ++jj) {
    int j2 = jb2 + jj;
    acc2[jj] = (j2 < 25) ? b2[j2] : 0.f;
  }
  for (int k2 = 0; k2 < 50; ++k2) {
    float v = u.h1[e2][k2];
#pragma unroll
    for (int jj = 0; jj < 13; ++jj) {
      int j2 = jb2 + jj;
      if (j2 < 25) acc2[jj] = fmaf(v, W2[k2 * 25 + j2], acc2[jj]);
    }
  }
  float part = 0.f;
#pragma unroll
  for (int jj = 0; jj < 13; ++jj) {
    int j2 = jb2 + jj;
    if (j2 < 25) part += fmaxf(acc2[jj], 0.f) * W3[j2];
  }
  p_s[hh][e2] = part;
  __syncthreads();
  if (t < 128 && (e0 + t) < n_edges) out[e0 + t] = p_s[0][t] + p_s[1][t] + b3[0];
}

// ---------- naive fallback (only if ws too small for P) ----------
__global__ __launch_bounds__(256, 2)
void edge_naive_kernel(const float* __restrict__ x, const float* __restrict__ ea,
                       const void* __restrict__ eidx,
                       const float* __restrict__ W1, const float* __restrict__ b1,
                       const float* __restrict__ W2, const float* __restrict__ b2,
                       const float* __restrict__ W3, const float* __restrict__ b3,
                       const int* __restrict__ flag, int use32_const,
                       float* __restrict__ out, int n_edges) {
  int e = blockIdx.x * blockDim.x + threadIdx.x;
  if (e >= n_edges) return;
  int use32 = flag ? *flag : use32_const;
  long s, d;
  if (use32) {
    s = ((const int*)eidx)[e];
    d = ((const int*)eidx)[(long)n_edges + e];
  } else {
    s = (long)((const long long*)eidx)[e];
    d = (long)((const long long*)eidx)[(long)n_edges + e];
  }
  float h1[50];
#pragma unroll
  for (int j = 0; j < 50; ++j) h1[j] = b1[j];
  for (int k = 0; k < 128; ++k) {
    float v = fmaxf(x[s * HID + k], 0.f);
#pragma unroll
    for (int j = 0; j < 50; ++j) h1[j] = fmaf(v, W1[k * 50 + j], h1[j]);
  }
  for (int k = 0; k < 128; ++k) {
    float v = fmaxf(x[d * HID + k], 0.f);
#pragma unroll
    for (int j = 0; j < 50; ++j) h1[j] = fmaf(v, W1[(128 + k) * 50 + j], h1[j]);
  }
  for (int k = 0; k < 128; ++k) {
    float v = ea[(long)e * HID + k];
#pragma unroll
    for (int j = 0; j < 50; ++j) h1[j] = fmaf(v, W1[(256 + k) * 50 + j], h1[j]);
  }
  float o = b3[0];
  for (int j2 = 0; j2 < 25; ++j2) {
    float h2 = b2[j2];
#pragma unroll 10
    for (int k = 0; k < 50; ++k) h2 = fmaf(fmaxf(h1[k], 0.f), W2[k * 25 + j2], h2);
    o = fmaf(fmaxf(h2, 0.f), W3[j2], o);
  }
  out[e] = o;
}

extern "C" void kernel_launch(void* const* d_in, const int* in_sizes, int n_in,
                              void* d_out, int out_size, void* d_ws, size_t ws_size,
                              hipStream_t stream) {
  const float* x  = (const float*)d_in[0];
  const float* ea = (const float*)d_in[1];
  const void*  ei = d_in[2];
  const float* W1 = (const float*)d_in[3];
  const float* b1 = (const float*)d_in[4];
  const float* W2 = (const float*)d_in[5];
  const float* b2 = (const float*)d_in[6];
  const float* W3 = (const float*)d_in[7];
  const float* b3 = (const float*)d_in[8];
  float* out = (float*)d_out;
  const int n_nodes = in_sizes[0] / HID;
  const int n_edges = in_sizes[1] / HID;
  const size_t pbytes = (size_t)n_nodes * PROW * sizeof(float);

  if (ws_size >= pbytes + sizeof(int)) {
    float* P  = (float*)d_ws;
    int* flag = (int*)((char*)d_ws + pbytes);
    hipLaunchKernelGGL(detect_idx_kernel, dim3(1), dim3(256), 0, stream,
                       (const unsigned int*)ei, flag);
    dim3 gp((n_nodes + 127) / 128, 2);
    hipLaunchKernelGGL(node_pre_kernel, gp, dim3(256), 0, stream, x, W1, P, n_nodes);
    dim3 ge((n_edges + 127) / 128);
    hipLaunchKernelGGL(edge_kernel, ge, dim3(256), 0, stream,
                       ea, ei, W1, b1, W2, b2, W3, b3, P, flag, out, n_edges);
  } else if (ws_size >= sizeof(int)) {
    int* flag = (int*)d_ws;
    hipLaunchKernelGGL(detect_idx_kernel, dim3(1), dim3(256), 0, stream,
                       (const unsigned int*)ei, flag);
    hipLaunchKernelGGL(edge_naive_kernel, dim3((n_edges + 255) / 256), dim3(256), 0, stream,
                       x, ea, ei, W1, b1, W2, b2, W3, b3, flag, 1, out, n_edges);
  } else {
    hipLaunchKernelGGL(edge_naive_kernel, dim3((n_edges + 255) / 256), dim3(256), 0, stream,
                       x, ea, ei, W1, b1, W2, b2, W3, b3, (const int*)nullptr, 1, out, n_edges);
  }
}

// Round 10
// 383.211 us; speedup vs baseline: 12.4364x; 1.0633x over previous
//
#include <hip/hip_runtime.h>

#define HID 128
#define PROW 104   // P row: src-half at [0..49], dst-half at [52..101]

// ---------- detect int32 vs int64 edge_index layout ----------
__global__ void detect_idx_kernel(const unsigned int* __restrict__ p, int* __restrict__ flag) {
  __shared__ int s;
  if (threadIdx.x == 0) s = 0;
  __syncthreads();
  if (p[2 * threadIdx.x + 1] != 0u) atomicOr(&s, 1);
  __syncthreads();
  if (threadIdx.x == 0) *flag = s;   // 1 -> int32 layout, 0 -> int64 layout
}

// ---------- node precompute: P[n][half*52+j] = relu(x[n]) @ W1[half*128 .. +127][j] ----------
__global__ __launch_bounds__(256, 4)
void node_pre_kernel(const float* __restrict__ x, const float* __restrict__ W1,
                     float* __restrict__ P, int n_nodes) {
  __shared__ __align__(16) float a_s[32][132];
  __shared__ __align__(16) float w_s[32][64];
  const int t = threadIdx.x;
  const int half = blockIdx.y;
  const int n0 = blockIdx.x * 128;
  const int jt = t & 15, rt = t >> 4;
  float acc[8][4];
#pragma unroll
  for (int i = 0; i < 8; ++i)
#pragma unroll
    for (int q = 0; q < 4; ++q) acc[i][q] = 0.f;

  for (int kc = 0; kc < 4; ++kc) {
#pragma unroll
    for (int i = 0; i < 4; ++i) {
      int f = t + 256 * i;
      int e = f >> 3;
      int k4 = (f & 7) << 2;
      int n = n0 + e;
      float4 v = make_float4(0.f, 0.f, 0.f, 0.f);
      if (n < n_nodes) v = *(const float4*)&x[(long)n * HID + kc * 32 + k4];
      a_s[k4 + 0][e] = fmaxf(v.x, 0.f);
      a_s[k4 + 1][e] = fmaxf(v.y, 0.f);
      a_s[k4 + 2][e] = fmaxf(v.z, 0.f);
      a_s[k4 + 3][e] = fmaxf(v.w, 0.f);
    }
#pragma unroll
    for (int i = 0; i < 8; ++i) {
      int f = t + 256 * i;
      int k = f >> 6, j = f & 63;
      float w = 0.f;
      if (j < 50) w = W1[(half * 128 + kc * 32 + k) * 50 + j];
      w_s[k][j] = w;
    }
    __syncthreads();
#pragma unroll 8
    for (int kk = 0; kk < 32; ++kk) {
      float4 w4 = *(const float4*)&w_s[kk][jt * 4];
      float4 a0 = *(const float4*)&a_s[kk][rt * 8];
      float4 a1 = *(const float4*)&a_s[kk][rt * 8 + 4];
      float av[8] = {a0.x, a0.y, a0.z, a0.w, a1.x, a1.y, a1.z, a1.w};
      float wv[4] = {w4.x, w4.y, w4.z, w4.w};
#pragma unroll
      for (int ri = 0; ri < 8; ++ri)
#pragma unroll
        for (int q = 0; q < 4; ++q) acc[ri][q] = fmaf(av[ri], wv[q], acc[ri][q]);
    }
    __syncthreads();
  }
  int jb = jt * 4;
  if (jb < 50) {
#pragma unroll
    for (int ri = 0; ri < 8; ++ri) {
      int n = n0 + rt * 8 + ri;
      if (n < n_nodes) {
#pragma unroll
        for (int q = 0; q < 4; ++q) {
          int j = jb + q;
          if (j < 50) P[(long)n * PROW + half * 52 + j] = acc[ri][q];
        }
      }
    }
  }
}

// ---------- fused edge kernel: barrier-free GEMM, scalar-pipe weights, reg accumulators ----------
__global__ __launch_bounds__(256, 3)
void edge_kernel(const float* __restrict__ ea, const void* __restrict__ eidx,
                 const float* __restrict__ W1, const float* __restrict__ b1,
                 const float* __restrict__ W2, const float* __restrict__ b2,
                 const float* __restrict__ W3, const float* __restrict__ b3,
                 const float* __restrict__ P, const int* __restrict__ flag,
                 float* __restrict__ out, int n_edges) {
  __shared__ float h1_s[128][53];   // layer-1 output exchange (53: bank-coprime)
  __shared__ float p_s[2][128];

  const int t = threadIdx.x;
  const int e0 = blockIdx.x * 128;
  const int e = t & 127;                                   // edge within tile
  const int h = __builtin_amdgcn_readfirstlane(t >> 7);    // j-half, wave-uniform -> SGPR
  const int ge = e0 + e;
  const bool ok = ge < n_edges;

  // edge endpoints (per-thread)
  const int use32 = *flag;
  long sidx = 0, didx = 0;
  if (ok) {
    if (use32) {
      sidx = ((const int*)eidx)[ge];
      didx = ((const int*)eidx)[(long)n_edges + ge];
    } else {
      sidx = (long)((const long long*)eidx)[ge];
      didx = (long)((const long long*)eidx)[(long)n_edges + ge];
    }
  }

  const float* __restrict__ myea = ea + (long)(ok ? ge : 0) * HID;

  float h1r[25];
#pragma unroll
  for (int jj = 0; jj < 25; ++jj) h1r[jj] = 0.f;

  // one 16-k chunk: 16 FMA-blocks of 25, W via uniform (scalar) loads
  auto comp16 = [&](int kbase, float4 A, float4 B, float4 C, float4 D) {
    float av[16] = {A.x, A.y, A.z, A.w, B.x, B.y, B.z, B.w,
                    C.x, C.y, C.z, C.w, D.x, D.y, D.z, D.w};
#pragma unroll
    for (int kk = 0; kk < 16; ++kk) {
      const float* __restrict__ wr = &W1[(long)(256 + kbase + kk) * 50 + h * 25];
#pragma unroll
      for (int jj = 0; jj < 25; ++jj) h1r[jj] = fmaf(av[kk], wr[jj], h1r[jj]);
    }
  };

  // K=128 in 8 chunks of 16, explicit 2-stage register double buffer, NO LDS, NO barriers
  float4 a0 = *(const float4*)(myea + 0);
  float4 a1 = *(const float4*)(myea + 4);
  float4 a2 = *(const float4*)(myea + 8);
  float4 a3 = *(const float4*)(myea + 12);
#pragma unroll 1
  for (int kc = 0; kc < 8; kc += 2) {
    const float* p1 = myea + (kc + 1) * 16;
    float4 c0 = *(const float4*)(p1 + 0);
    float4 c1 = *(const float4*)(p1 + 4);
    float4 c2 = *(const float4*)(p1 + 8);
    float4 c3 = *(const float4*)(p1 + 12);
    comp16(kc * 16, a0, a1, a2, a3);
    if (kc + 2 < 8) {
      const float* p2 = myea + (kc + 2) * 16;
      a0 = *(const float4*)(p2 + 0);
      a1 = *(const float4*)(p2 + 4);
      a2 = *(const float4*)(p2 + 8);
      a3 = *(const float4*)(p2 + 12);
    }
    comp16((kc + 1) * 16, c0, c1, c2, c3);
  }

  // layer-1 finish: P gather (per-lane scalar loads, L2/L3-resident) + bias + relu
  {
    const float* __restrict__ ps = &P[sidx * PROW + h * 25];
    const float* __restrict__ pd = &P[didx * PROW + 52 + h * 25];
#pragma unroll
    for (int jj = 0; jj < 25; ++jj) {
      float v = h1r[jj] + ps[jj] + pd[jj] + b1[h * 25 + jj];   // b1 uniform -> scalar
      h1_s[e][h * 25 + jj] = fmaxf(v, 0.f);
    }
  }
  __syncthreads();

  // layers 2 + 3: two threads per edge, 13/12 output cols; W2/W3/b2 uniform -> scalar
  const int jb2 = h * 13;
  float acc2[13];
#pragma unroll
  for (int jj = 0; jj < 13; ++jj) {
    int j2 = jb2 + jj;
    acc2[jj] = (j2 < 25) ? b2[j2] : 0.f;
  }
  for (int k2 = 0; k2 < 50; ++k2) {
    float v = h1_s[e][k2];
#pragma unroll
    for (int jj = 0; jj < 13; ++jj) {
      int j2 = jb2 + jj;
      if (j2 < 25) acc2[jj] = fmaf(v, W2[k2 * 25 + j2], acc2[jj]);
    }
  }
  float part = 0.f;
#pragma unroll
  for (int jj = 0; jj < 13; ++jj) {
    int j2 = jb2 + jj;
    if (j2 < 25) part += fmaxf(acc2[jj], 0.f) * W3[j2];
  }
  p_s[h][e] = part;
  __syncthreads();
  if (t < 128 && (e0 + t) < n_edges) out[e0 + t] = p_s[0][t] + p_s[1][t] + b3[0];
}

// ---------- naive fallback (only if ws too small for P) ----------
__global__ __launch_bounds__(256, 2)
void edge_naive_kernel(const float* __restrict__ x, const float* __restrict__ ea,
                       const void* __restrict__ eidx,
                       const float* __restrict__ W1, const float* __restrict__ b1,
                       const float* __restrict__ W2, const float* __restrict__ b2,
                       const float* __restrict__ W3, const float* __restrict__ b3,
                       const int* __restrict__ flag, int use32_const,
                       float* __restrict__ out, int n_edges) {
  int e = blockIdx.x * blockDim.x + threadIdx.x;
  if (e >= n_edges) return;
  int use32 = flag ? *flag : use32_const;
  long s, d;
  if (use32) {
    s = ((const int*)eidx)[e];
    d = ((const int*)eidx)[(long)n_edges + e];
  } else {
    s = (long)((const long long*)eidx)[e];
    d = (long)((const long long*)eidx)[(long)n_edges + e];
  }
  float h1[50];
#pragma unroll
  for (int j = 0; j < 50; ++j) h1[j] = b1[j];
  for (int k = 0; k < 128; ++k) {
    float v = fmaxf(x[s * HID + k], 0.f);
#pragma unroll
    for (int j = 0; j < 50; ++j) h1[j] = fmaf(v, W1[k * 50 + j], h1[j]);
  }
  for (int k = 0; k < 128; ++k) {
    float v = fmaxf(x[d * HID + k], 0.f);
#pragma unroll
    for (int j = 0; j < 50; ++j) h1[j] = fmaf(v, W1[(128 + k) * 50 + j], h1[j]);
  }
  for (int k = 0; k < 128; ++k) {
    float v = ea[(long)e * HID + k];
#pragma unroll
    for (int j = 0; j < 50; ++j) h1[j] = fmaf(v, W1[(256 + k) * 50 + j], h1[j]);
  }
  float o = b3[0];
  for (int j2 = 0; j2 < 25; ++j2) {
    float h2 = b2[j2];
#pragma unroll 10
    for (int k = 0; k < 50; ++k) h2 = fmaf(fmaxf(h1[k], 0.f), W2[k * 25 + j2], h2);
    o = fmaf(fmaxf(h2, 0.f), W3[j2], o);
  }
  out[e] = o;
}

extern "C" void kernel_launch(void* const* d_in, const int* in_sizes, int n_in,
                              void* d_out, int out_size, void* d_ws, size_t ws_size,
                              hipStream_t stream) {
  const float* x  = (const float*)d_in[0];
  const float* ea = (const float*)d_in[1];
  const void*  ei = d_in[2];
  const float* W1 = (const float*)d_in[3];
  const float* b1 = (const float*)d_in[4];
  const float* W2 = (const float*)d_in[5];
  const float* b2 = (const float*)d_in[6];
  const float* W3 = (const float*)d_in[7];
  const float* b3 = (const float*)d_in[8];
  float* out = (float*)d_out;
  const int n_nodes = in_sizes[0] / HID;
  const int n_edges = in_sizes[1] / HID;
  const size_t pbytes = (size_t)n_nodes * PROW * sizeof(float);

  if (ws_size >= pbytes + sizeof(int)) {
    float* P  = (float*)d_ws;
    int* flag = (int*)((char*)d_ws + pbytes);
    hipLaunchKernelGGL(detect_idx_kernel, dim3(1), dim3(256), 0, stream,
                       (const unsigned int*)ei, flag);
    dim3 gp((n_nodes + 127) / 128, 2);
    hipLaunchKernelGGL(node_pre_kernel, gp, dim3(256), 0, stream, x, W1, P, n_nodes);
    dim3 ge((n_edges + 127) / 128);
    hipLaunchKernelGGL(edge_kernel, ge, dim3(256), 0, stream,
                       ea, ei, W1, b1, W2, b2, W3, b3, P, flag, out, n_edges);
  } else if (ws_size >= sizeof(int)) {
    int* flag = (int*)d_ws;
    hipLaunchKernelGGL(detect_idx_kernel, dim3(1), dim3(256), 0, stream,
                       (const unsigned int*)ei, flag);
    hipLaunchKernelGGL(edge_naive_kernel, dim3((n_edges + 255) / 256), dim3(256), 0, stream,
                       x, ea, ei, W1, b1, W2, b2, W3, b3, flag, 1, out, n_edges);
  } else {
    hipLaunchKernelGGL(edge_naive_kernel, dim3((n_edges + 255) / 256), dim3(256), 0, stream,
                       x, ea, ei, W1, b1, W2, b2, W3, b3, (const int*)nullptr, 1, out, n_edges);
  }
}